// Round 1
// baseline (51.885 us; speedup 1.0000x reference)
//
#include <hip/hip_runtime.h>

#define QT 4
#define NM 1600
#define NC 91
#define BLOCK 256

__global__ __launch_bounds__(BLOCK, 4) void matcher_cost_kernel(
    const float* __restrict__ logits,   // [BQ, 91]
    const float* __restrict__ pboxes,   // [BQ, 4] cxcywh
    const int*   __restrict__ tlabels,  // [1600]
    const float* __restrict__ tboxes,   // [1600, 4] cxcywh
    float* __restrict__ out)            // [BQ, 1600]
{
    __shared__ float4 s_t[NM];          // target cxcywh
    __shared__ int    s_lab[NM];
    __shared__ float  s_prob[QT][NC + 1];

    const int tid = threadIdx.x;
    const int q0  = blockIdx.x * QT;

    // stage targets into LDS
    for (int i = tid; i < NM; i += BLOCK) {
        s_t[i]   = ((const float4*)tboxes)[i];
        s_lab[i] = tlabels[i];
    }

    // per-wave softmax: wave w handles query q0+w (91 classes across 64 lanes)
    {
        const int w = tid >> 6, lane = tid & 63;
        const float* lrow = logits + (size_t)(q0 + w) * NC;
        float v0 = (lane      < NC) ? lrow[lane]      : -3.4e38f;
        float v1 = (lane + 64 < NC) ? lrow[lane + 64] : -3.4e38f;
        float mx = fmaxf(v0, v1);
        #pragma unroll
        for (int off = 32; off; off >>= 1) mx = fmaxf(mx, __shfl_xor(mx, off));
        float e0 = (lane      < NC) ? __expf(v0 - mx) : 0.0f;
        float e1 = (lane + 64 < NC) ? __expf(v1 - mx) : 0.0f;
        float s = e0 + e1;
        #pragma unroll
        for (int off = 32; off; off >>= 1) s += __shfl_xor(s, off);
        float inv = 1.0f / s;
        if (lane      < NC) s_prob[w][lane]      = e0 * inv;
        if (lane + 64 < NC) s_prob[w][lane + 64] = e1 * inv;
    }
    __syncthreads();

    // main loop: for each query in tile, all 256 threads sweep the 1600 targets
    for (int wq = 0; wq < QT; ++wq) {
        const int q = q0 + wq;
        const float4 pb = ((const float4*)pboxes)[q];
        const float px0 = pb.x - 0.5f * pb.z, py0 = pb.y - 0.5f * pb.w;
        const float px1 = pb.x + 0.5f * pb.z, py1 = pb.y + 0.5f * pb.w;
        const float parea = pb.z * pb.w;
        const float* prob = s_prob[wq];
        float4* orow = (float4*)(out + (size_t)q * NM);

        for (int i = tid; i < NM / 4; i += BLOCK) {
            float r[4];
            #pragma unroll
            for (int j = 0; j < 4; ++j) {
                const int m = i * 4 + j;
                const float4 tb = s_t[m];
                // L1 cost on cxcywh
                float l1 = fabsf(pb.x - tb.x) + fabsf(pb.y - tb.y)
                         + fabsf(pb.z - tb.z) + fabsf(pb.w - tb.w);
                // target xyxy + area
                float tx0 = tb.x - 0.5f * tb.z, ty0 = tb.y - 0.5f * tb.w;
                float tx1 = tb.x + 0.5f * tb.z, ty1 = tb.y + 0.5f * tb.w;
                float tarea = tb.z * tb.w;
                // intersection
                float ix0 = fmaxf(px0, tx0), iy0 = fmaxf(py0, ty0);
                float ix1 = fminf(px1, tx1), iy1 = fminf(py1, ty1);
                float iw = fmaxf(ix1 - ix0, 0.0f), ih = fmaxf(iy1 - iy0, 0.0f);
                float inter = iw * ih;
                float uni = parea + tarea - inter;
                // enclosing box
                float ex0 = fminf(px0, tx0), ey0 = fminf(py0, ty0);
                float ex1 = fmaxf(px1, tx1), ey1 = fmaxf(py1, ty1);
                float earea = (ex1 - ex0) * (ey1 - ey0);
                // giou = iou - (earea - uni)/earea = inter/uni - 1 + uni/earea
                float giou = __fdividef(inter, uni) - 1.0f + __fdividef(uni, earea);
                float cls = prob[s_lab[m]];
                r[j] = 5.0f * l1 - cls - 2.0f * giou;
            }
            orow[i] = make_float4(r[0], r[1], r[2], r[3]);
        }
    }
}

extern "C" void kernel_launch(void* const* d_in, const int* in_sizes, int n_in,
                              void* d_out, int out_size, void* d_ws, size_t ws_size,
                              hipStream_t stream) {
    const float* logits  = (const float*)d_in[0];
    const float* pboxes  = (const float*)d_in[1];
    const int*   tlabels = (const int*)d_in[2];
    const float* tboxes  = (const float*)d_in[3];
    float* out = (float*)d_out;

    const int BQ = in_sizes[1] / 4;       // 14400
    const int grid = BQ / QT;             // 3600
    matcher_cost_kernel<<<grid, BLOCK, 0, stream>>>(logits, pboxes, tlabels, tboxes, out);
}

// Round 2
// 48.758 us; speedup vs baseline: 1.0641x; 1.0641x over previous
//
#include <hip/hip_runtime.h>

#define QT 4
#define NM 1600
#define NG (NM / 4)   // 400 groups of 4 targets
#define NC 91
#define BLOCK 256

__global__ __launch_bounds__(BLOCK, 4) void matcher_cost_kernel(
    const float* __restrict__ logits,   // [BQ, 91]
    const float* __restrict__ pboxes,   // [BQ, 4] cxcywh
    const int*   __restrict__ tlabels,  // [1600]
    const float* __restrict__ tboxes,   // [1600, 4] cxcywh
    float* __restrict__ out)            // [BQ, 1600]
{
    // SoA: one float4 = one component of 4 consecutive targets -> 16B lane
    // stride on ds_read_b128 (conflict-free), vs 64B stride before.
    __shared__ float4 s_cx[NG], s_cy[NG], s_w[NG], s_h[NG];
    __shared__ int4   s_lab[NG];
    __shared__ float  s_prob[QT][NC + 1];

    const int tid = threadIdx.x;
    const int q0  = blockIdx.x * QT;

    // stage targets AoS -> SoA
    for (int g = tid; g < NG; g += BLOCK) {
        const float4* tb4 = (const float4*)tboxes;
        float4 t0 = tb4[4 * g + 0], t1 = tb4[4 * g + 1];
        float4 t2 = tb4[4 * g + 2], t3 = tb4[4 * g + 3];
        s_cx[g] = make_float4(t0.x, t1.x, t2.x, t3.x);
        s_cy[g] = make_float4(t0.y, t1.y, t2.y, t3.y);
        s_w[g]  = make_float4(t0.z, t1.z, t2.z, t3.z);
        s_h[g]  = make_float4(t0.w, t1.w, t2.w, t3.w);
        s_lab[g] = ((const int4*)tlabels)[g];
    }

    // per-wave softmax: wave w handles query q0+w (91 classes over 64 lanes)
    {
        const int w = tid >> 6, lane = tid & 63;
        const float* lrow = logits + (size_t)(q0 + w) * NC;
        float v0 = (lane      < NC) ? lrow[lane]      : -3.4e38f;
        float v1 = (lane + 64 < NC) ? lrow[lane + 64] : -3.4e38f;
        float mx = fmaxf(v0, v1);
        #pragma unroll
        for (int off = 32; off; off >>= 1) mx = fmaxf(mx, __shfl_xor(mx, off));
        float e0 = (lane      < NC) ? __expf(v0 - mx) : 0.0f;
        float e1 = (lane + 64 < NC) ? __expf(v1 - mx) : 0.0f;
        float s = e0 + e1;
        #pragma unroll
        for (int off = 32; off; off >>= 1) s += __shfl_xor(s, off);
        float inv = 1.0f / s;
        if (lane      < NC) s_prob[w][lane]      = e0 * inv;
        if (lane + 64 < NC) s_prob[w][lane + 64] = e1 * inv;
    }

    // query constants in registers (hoisted out of the sweep)
    float qcx[QT], qcy[QT], qw[QT], qh[QT];
    float qx0[QT], qy0[QT], qx1[QT], qy1[QT], qa[QT];
    #pragma unroll
    for (int wq = 0; wq < QT; ++wq) {
        float4 pb = ((const float4*)pboxes)[q0 + wq];
        qcx[wq] = pb.x; qcy[wq] = pb.y; qw[wq] = pb.z; qh[wq] = pb.w;
        qx0[wq] = pb.x - 0.5f * pb.z; qy0[wq] = pb.y - 0.5f * pb.w;
        qx1[wq] = pb.x + 0.5f * pb.z; qy1[wq] = pb.y + 0.5f * pb.w;
        qa[wq]  = pb.z * pb.w;
    }

    __syncthreads();

    // sweep: load 4-target group ONCE, reuse across all QT queries
    for (int g = tid; g < NG; g += BLOCK) {
        float4 vcx = s_cx[g], vcy = s_cy[g], vw = s_w[g], vh = s_h[g];
        int4   vlab = s_lab[g];
        float tcx[4] = {vcx.x, vcx.y, vcx.z, vcx.w};
        float tcy[4] = {vcy.x, vcy.y, vcy.z, vcy.w};
        float tw[4]  = {vw.x,  vw.y,  vw.z,  vw.w};
        float th[4]  = {vh.x,  vh.y,  vh.z,  vh.w};
        int   lab[4] = {vlab.x, vlab.y, vlab.z, vlab.w};
        float tx0[4], ty0[4], tx1[4], ty1[4], ta[4];
        #pragma unroll
        for (int j = 0; j < 4; ++j) {
            tx0[j] = tcx[j] - 0.5f * tw[j];
            ty0[j] = tcy[j] - 0.5f * th[j];
            tx1[j] = tcx[j] + 0.5f * tw[j];
            ty1[j] = tcy[j] + 0.5f * th[j];
            ta[j]  = tw[j] * th[j];
        }
        #pragma unroll
        for (int wq = 0; wq < QT; ++wq) {
            float r[4];
            #pragma unroll
            for (int j = 0; j < 4; ++j) {
                float l1 = fabsf(qcx[wq] - tcx[j]) + fabsf(qcy[wq] - tcy[j])
                         + fabsf(qw[wq]  - tw[j])  + fabsf(qh[wq]  - th[j]);
                float ix0 = fmaxf(qx0[wq], tx0[j]), iy0 = fmaxf(qy0[wq], ty0[j]);
                float ix1 = fminf(qx1[wq], tx1[j]), iy1 = fminf(qy1[wq], ty1[j]);
                float iw = fmaxf(ix1 - ix0, 0.0f), ih = fmaxf(iy1 - iy0, 0.0f);
                float inter = iw * ih;
                float uni = qa[wq] + ta[j] - inter;
                float ex0 = fminf(qx0[wq], tx0[j]), ey0 = fminf(qy0[wq], ty0[j]);
                float ex1 = fmaxf(qx1[wq], tx1[j]), ey1 = fmaxf(qy1[wq], ty1[j]);
                float earea = (ex1 - ex0) * (ey1 - ey0);
                // giou = inter/uni - 1 + uni/earea
                float giou = __fdividef(inter, uni) - 1.0f + __fdividef(uni, earea);
                float cls = s_prob[wq][lab[j]];
                r[j] = 5.0f * l1 - cls - 2.0f * giou;
            }
            ((float4*)(out + (size_t)(q0 + wq) * NM))[g] =
                make_float4(r[0], r[1], r[2], r[3]);
        }
    }
}

extern "C" void kernel_launch(void* const* d_in, const int* in_sizes, int n_in,
                              void* d_out, int out_size, void* d_ws, size_t ws_size,
                              hipStream_t stream) {
    const float* logits  = (const float*)d_in[0];
    const float* pboxes  = (const float*)d_in[1];
    const int*   tlabels = (const int*)d_in[2];
    const float* tboxes  = (const float*)d_in[3];
    float* out = (float*)d_out;

    const int BQ = in_sizes[1] / 4;   // 14400
    const int grid = BQ / QT;         // 3600
    matcher_cost_kernel<<<grid, BLOCK, 0, stream>>>(logits, pboxes, tlabels, tboxes, out);
}